// Round 9
// baseline (24.480 us; speedup 1.0000x reference)
//
#include <hip/hip_runtime.h>
#include <math.h>

constexpr int DIM = 16;
constexpr int NBR = 8;     // batch rows per block
constexpr int NS  = 2;     // sample tiles (split-K; last-arriving block merges)
constexpr int BT  = 512;   // threads per block
constexpr int NW  = BT / 64;

typedef float v2f __attribute__((ext_vector_type(2)));

// ---------------------------------------------------------------------------
// Split-sample fused kernel (single dispatch + memset node).
//   score(b,s) = sum_d ( c[b,d]*p^2 + a[b,d]*p ),  p = prior[s,d]
//   a = mu/sigma^2, c = 0.5*(1 - 1/sigma^2)   (per-b const dropped; nlp absorbed)
// Grid (bs/NBR, NS). Block (bg,t) scores rows bg*8..+7 against tile t
// (n/NS samples), writes packed partial (idx<<32|scorebits) per row with
// agent-scope atomics; atomicAdd on cnt[bg] -- the SECOND block to finish
// merges both tiles and gathers (deterministic: explicit idx tie-break).
// ---------------------------------------------------------------------------
__global__ __launch_bounds__(BT) void pfr_split_kernel(
    const float* __restrict__ mu_q, const float* __restrict__ std_q,
    const float* __restrict__ prior,
    unsigned long long* __restrict__ part,   // [bs][NS]
    int* __restrict__ cnt,                   // [bs/NBR], zeroed each call
    float* __restrict__ out_samples, float* __restrict__ out_idx,
    int n_samples, int bs)
{
    const int bg   = blockIdx.x;
    const int tile = blockIdx.y;
    const int b0   = bg * NBR;
    const int spt  = n_samples / NS;          // 2048
    const int s0   = tile * spt;
    const int tid  = threadIdx.x;

    __shared__ float a_l[NBR * DIM];
    __shared__ float c_l[NBR * DIM];

    // ---- cooperative coefficient setup (same arithmetic as R7/R8) ----
    if (tid < NBR * DIM) {
        const int gi = b0 * DIM + tid;
        const float sd = std_q[gi];
        const float w  = 1.0f / (sd * sd);
        a_l[tid] = mu_q[gi] * w;
        c_l[tid] = 0.5f - 0.5f * w;
    }
    __syncthreads();

    // ---- load this thread's 4 sample rows into registers ----
    const int sbase = s0 + tid;
    v2f p2[4][8];
#pragma unroll
    for (int k = 0; k < 4; ++k) {
        const float4* rp = reinterpret_cast<const float4*>(
            prior + (size_t)(sbase + k * BT) * DIM);
        float4 q0 = rp[0], q1 = rp[1], q2 = rp[2], q3 = rp[3];
        p2[k][0] = (v2f){q0.x, q0.y}; p2[k][1] = (v2f){q0.z, q0.w};
        p2[k][2] = (v2f){q1.x, q1.y}; p2[k][3] = (v2f){q1.z, q1.w};
        p2[k][4] = (v2f){q2.x, q2.y}; p2[k][5] = (v2f){q2.z, q2.w};
        p2[k][6] = (v2f){q3.x, q3.y}; p2[k][7] = (v2f){q3.z, q3.w};
    }

    float best[NBR]; int bidx[NBR];
#pragma unroll
    for (int r = 0; r < NBR; ++r) { best[r] = -INFINITY; bidx[r] = 0x7fffffff; }

    // ---- score: row-coeffs broadcast from LDS once per r, 4 samples each ----
#pragma unroll
    for (int r = 0; r < NBR; ++r) {
        const float4* av = reinterpret_cast<const float4*>(a_l + r * DIM);
        const float4* cv = reinterpret_cast<const float4*>(c_l + r * DIM);
        v2f a2[8], c2[8];
#pragma unroll
        for (int i = 0; i < 4; ++i) {
            float4 va = av[i], vc = cv[i];
            a2[2*i+0] = (v2f){va.x, va.y};  a2[2*i+1] = (v2f){va.z, va.w};
            c2[2*i+0] = (v2f){vc.x, vc.y};  c2[2*i+1] = (v2f){vc.z, vc.w};
        }
#pragma unroll
        for (int k = 0; k < 4; ++k) {
            v2f acc = (v2f){0.0f, 0.0f};
#pragma unroll
            for (int i = 0; i < 8; ++i) {
                v2f t = __builtin_elementwise_fma(c2[i], p2[k][i], a2[i]);
                acc   = __builtin_elementwise_fma(p2[k][i], t, acc);
            }
            const float sc = acc.x + acc.y;
            const int   s  = sbase + k * BT;       // k ascending -> s ascending
            if (sc > best[r]) { best[r] = sc; bidx[r] = s; }
        }
    }

    // ---- wave butterfly (explicit smaller-idx tie-break) ----
#pragma unroll
    for (int off = 32; off >= 1; off >>= 1) {
#pragma unroll
        for (int r = 0; r < NBR; ++r) {
            const float ob = __shfl_xor(best[r], off, 64);
            const int   oi = __shfl_xor(bidx[r], off, 64);
            if (ob > best[r] || (ob == best[r] && oi < bidx[r])) {
                best[r] = ob; bidx[r] = oi;
            }
        }
    }

    // ---- cross-wave merge via tiny LDS ----
    __shared__ float wv[NW][NBR];
    __shared__ int   wi[NW][NBR];
    const int wave = tid >> 6;
    if ((tid & 63) == 0) {
#pragma unroll
        for (int r = 0; r < NBR; ++r) { wv[wave][r] = best[r]; wi[wave][r] = bidx[r]; }
    }
    __syncthreads();

    if (tid < NBR) {
        float bb = wv[0][tid]; int bbi = wi[0][tid];
#pragma unroll
        for (int w = 1; w < NW; ++w) {
            const float ob = wv[w][tid]; const int oi = wi[w][tid];
            if (ob > bb || (ob == bb && oi < bbi)) { bb = ob; bbi = oi; }
        }
        const unsigned long long pk =
            ((unsigned long long)(unsigned int)bbi << 32) |
            (unsigned long long)(unsigned int)__float_as_uint(bb);
        __hip_atomic_store(&part[(size_t)(b0 + tid) * NS + tile], pk,
                           __ATOMIC_RELAXED, __HIP_MEMORY_SCOPE_AGENT);
    }
    __syncthreads();   // all 8 partial stores issued & retired before the count

    // ---- last-arriver merges (no spin; order-independent result) ----
    __shared__ int s_second;
    if (tid == 0) {
        const int old = __hip_atomic_fetch_add(&cnt[bg], 1, __ATOMIC_ACQ_REL,
                                               __HIP_MEMORY_SCOPE_AGENT);
        s_second = (old == 1);
    }
    __syncthreads();

    if (s_second && tid < NBR) {
        const int b = b0 + tid;
        const unsigned long long v0 = __hip_atomic_load(
            &part[(size_t)b * NS + 0], __ATOMIC_RELAXED, __HIP_MEMORY_SCOPE_AGENT);
        const unsigned long long v1 = __hip_atomic_load(
            &part[(size_t)b * NS + 1], __ATOMIC_RELAXED, __HIP_MEMORY_SCOPE_AGENT);
        const float f0 = __uint_as_float((unsigned int)v0);
        const float f1 = __uint_as_float((unsigned int)v1);
        const int   i0 = (int)(v0 >> 32);
        const int   i1 = (int)(v1 >> 32);
        float bb; int bbi;
        if (f0 > f1 || (f0 == f1 && i0 < i1)) { bb = f0; bbi = i0; }
        else                                  { bb = f1; bbi = i1; }
        (void)bb;
        out_idx[b] = (float)bbi;
        const float4* r4 = reinterpret_cast<const float4*>(prior + (size_t)bbi * DIM);
        float4* o = reinterpret_cast<float4*>(out_samples + (size_t)b * DIM);
        o[0] = r4[0]; o[1] = r4[1]; o[2] = r4[2]; o[3] = r4[3];
    }
}

extern "C" void kernel_launch(void* const* d_in, const int* in_sizes, int n_in,
                              void* d_out, int out_size, void* d_ws, size_t ws_size,
                              hipStream_t stream)
{
    const float* mu_q  = (const float*)d_in[0];   // [bs,16]
    const float* std_q = (const float*)d_in[1];   // [bs,16]
    const float* prior = (const float*)d_in[2];   // [n,16]
    // d_in[3] (normal_log_prob) algebraically absorbed -- unused.

    const int bs        = in_sizes[0] / DIM;      // 1024
    const int n_samples = in_sizes[2] / DIM;      // 4096
    const int ngroups   = bs / NBR;               // 128

    float* out_samples = (float*)d_out;                       // [bs,16]
    float* out_idx     = (float*)d_out + (size_t)bs * DIM;    // [bs]

    int*                cnt  = (int*)d_ws;                    // [ngroups]
    unsigned long long* part = (unsigned long long*)((char*)d_ws + 512); // [bs][NS]

    hipMemsetAsync(cnt, 0, ngroups * sizeof(int), stream);    // capture-legal

    dim3 grid(ngroups, NS);                       // 128 x 2 = 256 blocks
    pfr_split_kernel<<<grid, BT, 0, stream>>>(
        mu_q, std_q, prior, part, cnt, out_samples, out_idx, n_samples, bs);
}

// Round 10
// 13.365 us; speedup vs baseline: 1.8316x; 1.8316x over previous
//
#include <hip/hip_runtime.h>
#include <math.h>

constexpr int DIM = 16;
constexpr int NB  = 4;     // batch rows per block
constexpr int BT  = 512;   // threads per block (8 waves, 2/SIMD, 1 block/CU)
constexpr int NW  = BT / 64;

typedef float v2f __attribute__((ext_vector_type(2)));

// ---------------------------------------------------------------------------
// Single fused kernel (one dispatch -- any extra graph node costs ~5 us on
// this harness, see R2/R5/R9).
//   score(b,s) = sum_d ( c[b,d]*p^2 + a[b,d]*p ),  p = prior[s,d]
//   a = mu/sigma^2, c = 0.5*(1 - 1/sigma^2)
// (reference's perturbed[b,s] up to a per-b additive constant -- argmax-
//  invariant; normal_log_prob algebraically absorbed: nlp = -0.5 p^2 - K.)
// Inner product issued as v_pk_fma_f32 (2 f32 FMAs/instr) on even/odd dim
// pairs. Coefficients computed cooperatively (64 divides per block total),
// broadcast via LDS. Kernel ~2.1 us vs ~1.8 us per-CU L2-path floor.
// ---------------------------------------------------------------------------
__global__ __launch_bounds__(BT) void pfr_fused_kernel(
    const float* __restrict__ mu_q, const float* __restrict__ std_q,
    const float* __restrict__ prior,
    float* __restrict__ out_samples, float* __restrict__ out_idx,
    int n_samples, int bs)
{
    const int b0  = blockIdx.x * NB;
    const int tid = threadIdx.x;

    __shared__ float a_l[NB * DIM];
    __shared__ float c_l[NB * DIM];

    // ---- cooperative coefficient setup: one (r,d) pair per thread<64 ----
    if (tid < NB * DIM) {
        const int gi = b0 * DIM + tid;
        const float sd = std_q[gi];
        const float w  = 1.0f / (sd * sd);
        a_l[tid] = mu_q[gi] * w;
        c_l[tid] = 0.5f - 0.5f * w;
    }
    __syncthreads();

    // ---- broadcast coefficients to registers as even/odd v2f pairs ----
    v2f a2[NB][8], c2[NB][8];
#pragma unroll
    for (int r = 0; r < NB; ++r) {
        const float4* av = reinterpret_cast<const float4*>(a_l + r * DIM);
        const float4* cv = reinterpret_cast<const float4*>(c_l + r * DIM);
#pragma unroll
        for (int i = 0; i < 4; ++i) {
            float4 va = av[i], vc = cv[i];
            a2[r][2*i+0] = (v2f){va.x, va.y};  a2[r][2*i+1] = (v2f){va.z, va.w};
            c2[r][2*i+0] = (v2f){vc.x, vc.y};  c2[r][2*i+1] = (v2f){vc.z, vc.w};
        }
    }

    float best[NB]; int bidx[NB];
#pragma unroll
    for (int r = 0; r < NB; ++r) { best[r] = -INFINITY; bidx[r] = 0x7fffffff; }

    // ---- scan: each thread handles n/BT sample rows, shared across NB ----
    const int iters = n_samples / BT;            // 8 for n=4096
    for (int k = 0; k < iters; ++k) {
        const int s = tid + k * BT;
        const float4* rp = reinterpret_cast<const float4*>(prior + (size_t)s * DIM);
        float4 q0 = rp[0], q1 = rp[1], q2 = rp[2], q3 = rp[3];
        v2f p2[8] = { (v2f){q0.x, q0.y}, (v2f){q0.z, q0.w},
                      (v2f){q1.x, q1.y}, (v2f){q1.z, q1.w},
                      (v2f){q2.x, q2.y}, (v2f){q2.z, q2.w},
                      (v2f){q3.x, q3.y}, (v2f){q3.z, q3.w} };
#pragma unroll
        for (int r = 0; r < NB; ++r) {
            v2f acc = (v2f){0.0f, 0.0f};
#pragma unroll
            for (int i = 0; i < 8; ++i) {
                // acc += p * (c*p + a)   -- both as v_pk_fma_f32
                v2f t = __builtin_elementwise_fma(c2[r][i], p2[i], a2[r][i]);
                acc   = __builtin_elementwise_fma(p2[i], t, acc);
            }
            const float sc = acc.x + acc.y;
            // s ascends per thread -> strict '>' keeps first (smallest) idx
            if (sc > best[r]) { best[r] = sc; bidx[r] = s; }
        }
    }

    // ---- wave (64-lane) butterfly, explicit smaller-idx tie-break ----
#pragma unroll
    for (int off = 32; off >= 1; off >>= 1) {
#pragma unroll
        for (int r = 0; r < NB; ++r) {
            const float ob = __shfl_xor(best[r], off, 64);
            const int   oi = __shfl_xor(bidx[r], off, 64);
            if (ob > best[r] || (ob == best[r] && oi < bidx[r])) {
                best[r] = ob; bidx[r] = oi;
            }
        }
    }

    // ---- cross-wave merge via tiny LDS ----
    __shared__ float wv[NW][NB];
    __shared__ int   wi[NW][NB];
    const int wave = tid >> 6;
    if ((tid & 63) == 0) {
#pragma unroll
        for (int r = 0; r < NB; ++r) { wv[wave][r] = best[r]; wi[wave][r] = bidx[r]; }
    }
    __syncthreads();

    if (tid < NB && (b0 + tid) < bs) {
        float bb = wv[0][tid]; int bbi = wi[0][tid];
#pragma unroll
        for (int w = 1; w < NW; ++w) {
            const float ob = wv[w][tid]; const int oi = wi[w][tid];
            if (ob > bb || (ob == bb && oi < bbi)) { bb = ob; bbi = oi; }
        }
        out_idx[b0 + tid] = (float)bbi;
        const float4* r4 = reinterpret_cast<const float4*>(prior + (size_t)bbi * DIM);
        float4* o = reinterpret_cast<float4*>(out_samples + (size_t)(b0 + tid) * DIM);
        o[0] = r4[0]; o[1] = r4[1]; o[2] = r4[2]; o[3] = r4[3];
    }
}

extern "C" void kernel_launch(void* const* d_in, const int* in_sizes, int n_in,
                              void* d_out, int out_size, void* d_ws, size_t ws_size,
                              hipStream_t stream)
{
    const float* mu_q  = (const float*)d_in[0];   // [bs,16]
    const float* std_q = (const float*)d_in[1];   // [bs,16]
    const float* prior = (const float*)d_in[2];   // [n,16]
    // d_in[3] (normal_log_prob) algebraically absorbed -- unused.

    const int bs        = in_sizes[0] / DIM;      // 1024
    const int n_samples = in_sizes[2] / DIM;      // 4096

    float* out_samples = (float*)d_out;                       // [bs,16]
    float* out_idx     = (float*)d_out + (size_t)bs * DIM;    // [bs]

    const int nblocks = (bs + NB - 1) / NB;       // 256
    pfr_fused_kernel<<<nblocks, BT, 0, stream>>>(
        mu_q, std_q, prior, out_samples, out_idx, n_samples, bs);
}